// Round 2
// baseline (1147.810 us; speedup 1.0000x reference)
//
#include <hip/hip_runtime.h>

typedef __attribute__((ext_vector_type(8))) __bf16 bf16x8;
typedef __attribute__((ext_vector_type(4))) float f32x4;

#define DEV static __device__ __forceinline__

// B=4, C=64, P=256, D=512, H=8, R=64
#define NB 4
#define NC 64
#define NP 256
#define ND 512
#define NH 8
#define NR 64
#define CPD (NC * NP * ND)  // 8,388,608 elems per batch

// async global->LDS, 16B/lane; lds dest is wave-uniform base (+lane*16 by HW)
DEV void gll16(const void* g, void* l) {
  __builtin_amdgcn_global_load_lds(
      (const __attribute__((address_space(1))) unsigned int*)g,
      (__attribute__((address_space(3))) unsigned int*)l, 16, 0, 0);
}

// ---------------- prep ----------------

__global__ __launch_bounds__(256) void cvt_copy(const float* __restrict__ src,
                                                __bf16* __restrict__ dst, long n) {
  long i = ((long)blockIdx.x * 256 + threadIdx.x) * 8;
  if (i + 8 > n) return;
  f32x4 a = *(const f32x4*)(src + i);
  f32x4 b = *(const f32x4*)(src + i + 4);
  bf16x8 o;
  o[0] = (__bf16)a[0]; o[1] = (__bf16)a[1]; o[2] = (__bf16)a[2]; o[3] = (__bf16)a[3];
  o[4] = (__bf16)b[0]; o[5] = (__bf16)b[1]; o[6] = (__bf16)b[2]; o[7] = (__bf16)b[3];
  *(bf16x8*)(dst + i) = o;
}

__global__ __launch_bounds__(256) void fill_tables(float* __restrict__ ctab,
                                                   float* __restrict__ stab) {
  int idx = blockIdx.x * 256 + threadIdx.x;  // 16384 = 256 pos x 64
  int p = idx >> 6, j = idx & 63, i = j & 31;
  float freq = powf(10000.0f, -(float)i * (1.0f / 32.0f));
  float ang = (float)p * freq;
  ctab[idx] = cosf(ang);
  stab[idx] = sinf(ang);
}

// in-place RoPE (+optional bias) on per-batch [C][P][H][R] bf16.
__global__ __launch_bounds__(256) void rope_k(__bf16* __restrict__ x,
                                              const float* __restrict__ ctab,
                                              const float* __restrict__ stab,
                                              const float* __restrict__ bias,
                                              int is_chan, int b) {
  int tid = blockIdx.x * 256 + threadIdx.x;  // 524,288 threads (C*P*H*4)
  int g = tid >> 2;                          // [0, 131072)
  int r0 = (tid & 3) * 8;                    // 0,8,16,24  (< 32)
  int h = g & 7, pp = (g >> 3) & 255, c = g >> 11;
  int s = is_chan ? c : pp;
  long base = (long)g * 64;
  bf16x8 x1 = *(bf16x8*)(x + base + r0);
  bf16x8 x2 = *(bf16x8*)(x + base + 32 + r0);
  const float* cp = ctab + s * 64 + r0;
  const float* sp = stab + s * 64 + r0;
  float b1[8] = {0, 0, 0, 0, 0, 0, 0, 0}, b2[8] = {0, 0, 0, 0, 0, 0, 0, 0};
  if (bias != nullptr) {
    const float* bp = bias + (((long)b * 256 + pp) * 8 + h) * 64 + r0;
#pragma unroll
    for (int j = 0; j < 8; j++) { b1[j] = bp[j]; b2[j] = bp[j + 32]; }
  }
  bf16x8 y1, y2;
#pragma unroll
  for (int j = 0; j < 8; j++) {
    float v1 = (float)x1[j] + b1[j];
    float v2 = (float)x2[j] + b2[j];
    float cc = cp[j], ss = sp[j];
    y1[j] = (__bf16)(v1 * cc - v2 * ss);
    y2[j] = (__bf16)(v2 * cc + v1 * ss);
  }
  *(bf16x8*)(x + base + r0) = y1;
  *(bf16x8*)(x + base + 32 + r0) = y2;
}

// per-c transpose of one batch: qz_b f32 [c][256 p][512 d] -> out bf16 [c][512 d][256 p]
__global__ __launch_bounds__(256) void t_time(const float* __restrict__ qzb,
                                              __bf16* __restrict__ out) {
  __shared__ float lds[64][65];
  const int t = threadIdx.x;
  const int c = blockIdx.y;
  const int dt = blockIdx.x >> 2, pt = blockIdx.x & 3;
  const long ibase = (long)c * (NP * ND) + (long)pt * 64 * ND + dt * 64;
#pragma unroll
  for (int pass = 0; pass < 4; pass++) {
    int idx = pass * 256 + t;
    int pr = idx >> 4, dc = (idx & 15) * 4;
    f32x4 v = *(const f32x4*)(qzb + ibase + (long)pr * ND + dc);
    lds[pr][dc] = v[0]; lds[pr][dc + 1] = v[1]; lds[pr][dc + 2] = v[2]; lds[pr][dc + 3] = v[3];
  }
  __syncthreads();
  const long obase = (long)c * (ND * NP) + (long)dt * 64 * NP + pt * 64;
#pragma unroll
  for (int pass = 0; pass < 2; pass++) {
    int idx = pass * 256 + t;
    int dr = idx >> 3, pc = (idx & 7) * 8;
    bf16x8 o;
#pragma unroll
    for (int j = 0; j < 8; j++) o[j] = (__bf16)lds[pc + j][dr];
    *(bf16x8*)(out + obase + (long)dr * NP + pc) = o;
  }
}

// per-p transpose of one batch: qz_b f32 [64 c][512 d] (c-stride P*D) -> out bf16 [p][512 d][64 c]
__global__ __launch_bounds__(256) void t_chan(const float* __restrict__ qzb,
                                              __bf16* __restrict__ out) {
  __shared__ float lds[64][65];
  const int t = threadIdx.x;
  const int p = blockIdx.y, dt = blockIdx.x;
  const long ibase = (long)p * ND + dt * 64;
  const long cstride = (long)NP * ND;
#pragma unroll
  for (int pass = 0; pass < 4; pass++) {
    int idx = pass * 256 + t;
    int cr = idx >> 4, dc = (idx & 15) * 4;
    f32x4 v = *(const f32x4*)(qzb + ibase + (long)cr * cstride + dc);
    lds[cr][dc] = v[0]; lds[cr][dc + 1] = v[1]; lds[cr][dc + 2] = v[2]; lds[cr][dc + 3] = v[3];
  }
  __syncthreads();
  const long obase = (long)p * (ND * NC) + (long)dt * 64 * NC;
#pragma unroll
  for (int pass = 0; pass < 2; pass++) {
    int idx = pass * 256 + t;
    int dr = idx >> 3, cc = (idx & 7) * 8;
    bf16x8 o;
#pragma unroll
    for (int j = 0; j < 8; j++) o[j] = (__bf16)lds[cc + j][dr];
    *(bf16x8*)(out + obase + (long)dr * NC + cc) = o;
  }
}

// ---------------- generic BT-GEMM ----------------
// C[M x N] = A[M x K] * B[N x K]^T, bf16 in, f32 acc. Exact tiles only.
// LDS rows = 64 k-elems (128B), XOR-swizzled ((row&7)<<4); source pre-swizzled so
// global_load_lds writes linearly (both-sides involution, guide rule #21).
template <int BM, int BN, int WR, int WC, bool OUTBF>
__global__ __launch_bounds__(256) void bt_gemm(
    const __bf16* __restrict__ A, long As, int lda,
    const __bf16* __restrict__ Bm, long Bs, int ldb,
    void* __restrict__ Cb, long ldc, int cdiv, long cs1, long cs2,
    int K, int ntiles) {
  constexpr int WM = BM / WR, WN = BN / WC;
  constexpr int MF = WM / 16, NF = WN / 16;
  constexpr int ISSA = BM / 32, ISSB = BN / 32;
  __shared__ __bf16 ldsA[BM * 64];
  __shared__ __bf16 ldsB[BN * 64];
  const int t = threadIdx.x;
  const int lane = t & 63, wid = t >> 6;
  const int z = blockIdx.y;
  const int mt = blockIdx.x / ntiles, nt = blockIdx.x % ntiles;
  const __bf16* Ab = A + (long)z * As + (long)mt * BM * lda;
  const __bf16* Bb = Bm + (long)z * Bs + (long)nt * BN * ldb;
  const int wrow = wid % WR, wcol = wid / WR;
  const int woffm = wrow * WM, woffn = wcol * WN;

  f32x4 acc[MF][NF];
#pragma unroll
  for (int fm = 0; fm < MF; fm++)
#pragma unroll
    for (int fn = 0; fn < NF; fn++)
#pragma unroll
      for (int q = 0; q < 4; q++) acc[fm][fn][q] = 0.0f;

  for (int k0 = 0; k0 < K; k0 += 64) {
    __syncthreads();
#pragma unroll
    for (int i = 0; i < ISSA; i++) {
      int chunk = i * 256 + t;
      int row = chunk >> 3;
      int src = ((chunk & 7) * 16) ^ ((row & 7) << 4);
      gll16(Ab + (long)row * lda + k0 + (src >> 1),
            (char*)ldsA + i * 4096 + wid * 1024);
    }
#pragma unroll
    for (int i = 0; i < ISSB; i++) {
      int chunk = i * 256 + t;
      int row = chunk >> 3;
      int src = ((chunk & 7) * 16) ^ ((row & 7) << 4);
      gll16(Bb + (long)row * ldb + k0 + (src >> 1),
            (char*)ldsB + i * 4096 + wid * 1024);
    }
    __syncthreads();
#pragma unroll
    for (int ks = 0; ks < 2; ks++) {
      bf16x8 af[MF], bfr[NF];
#pragma unroll
      for (int fm = 0; fm < MF; fm++) {
        int row = woffm + fm * 16 + (lane & 15);
        int byt = (row * 128 + ks * 64 + ((lane >> 4) << 4)) ^ ((row & 7) << 4);
        af[fm] = *(const bf16x8*)((const char*)ldsA + byt);
      }
#pragma unroll
      for (int fn = 0; fn < NF; fn++) {
        int row = woffn + fn * 16 + (lane & 15);
        int byt = (row * 128 + ks * 64 + ((lane >> 4) << 4)) ^ ((row & 7) << 4);
        bfr[fn] = *(const bf16x8*)((const char*)ldsB + byt);
      }
#pragma unroll
      for (int fm = 0; fm < MF; fm++)
#pragma unroll
        for (int fn = 0; fn < NF; fn++)
          acc[fm][fn] = __builtin_amdgcn_mfma_f32_16x16x32_bf16(af[fm], bfr[fn], acc[fm][fn], 0, 0, 0);
    }
  }
  const long coff = (long)(z / cdiv) * cs1 + (long)(z % cdiv) * cs2;
#pragma unroll
  for (int fm = 0; fm < MF; fm++)
#pragma unroll
    for (int fn = 0; fn < NF; fn++)
#pragma unroll
      for (int i = 0; i < 4; i++) {
        long row = (long)mt * BM + woffm + fm * 16 + ((lane >> 4) << 2) + i;
        long col = (long)nt * BN + woffn + fn * 16 + (lane & 15);
        float v = acc[fm][fn][i];
        if (OUTBF)
          ((__bf16*)Cb)[coff + row * ldc + col] = (__bf16)v;
        else
          ((float*)Cb)[coff + row * ldc + col] = v;
      }
}

// ---------------- fused scores+softmax+head-average ----------------
// time, per c of one batch: S_h = Q_h K_h^T / 64, softmax over q, avg over 8 heads.
__global__ __launch_bounds__(256) void time_scores(const __bf16* __restrict__ qu,
                                                   const __bf16* __restrict__ qv,
                                                   __bf16* __restrict__ avg) {
  __shared__ __bf16 ldsK[256 * 64];
  const int t = threadIdx.x, lane = t & 63, wid = t >> 6;
  const int c = blockIdx.y, pblk = blockIdx.x;
  const long base = (long)c * (NP * ND);
  const int p0 = pblk * 64 + wid * 16;
  f32x4 avgacc[16];
#pragma unroll
  for (int f = 0; f < 16; f++)
#pragma unroll
    for (int q = 0; q < 4; q++) avgacc[f][q] = 0.0f;

  for (int h = 0; h < 8; h++) {
    __syncthreads();
#pragma unroll
    for (int i = 0; i < 8; i++) {  // stage K_h [256 q][64 r], swizzled
      int chunk = i * 256 + t;
      int row = chunk >> 3;
      int src = ((chunk & 7) * 16) ^ ((row & 7) << 4);
      gll16(qv + base + (long)row * ND + h * 64 + (src >> 1),
            (char*)ldsK + i * 4096 + wid * 1024);
    }
    __syncthreads();
    bf16x8 aq[2];
#pragma unroll
    for (int ks = 0; ks < 2; ks++)
      aq[ks] = *(const bf16x8*)(qu + base + (long)(p0 + (lane & 15)) * ND + h * 64 +
                                ks * 32 + ((lane >> 4) << 3));
    f32x4 acc[16];
#pragma unroll
    for (int f = 0; f < 16; f++)
#pragma unroll
      for (int q = 0; q < 4; q++) acc[f][q] = 0.0f;
#pragma unroll
    for (int ks = 0; ks < 2; ks++)
#pragma unroll
      for (int nf = 0; nf < 16; nf++) {
        int row = nf * 16 + (lane & 15);
        int byt = (row * 128 + ks * 64 + ((lane >> 4) << 4)) ^ ((row & 7) << 4);
        bf16x8 bfrag = *(const bf16x8*)((const char*)ldsK + byt);
        acc[nf] = __builtin_amdgcn_mfma_f32_16x16x32_bf16(aq[ks], bfrag, acc[nf], 0, 0, 0);
      }
#pragma unroll
    for (int i = 0; i < 4; i++) {
      float m = acc[0][i];
#pragma unroll
      for (int nf = 1; nf < 16; nf++) m = fmaxf(m, acc[nf][i]);
      m = fmaxf(m, __shfl_xor(m, 1));
      m = fmaxf(m, __shfl_xor(m, 2));
      m = fmaxf(m, __shfl_xor(m, 4));
      m = fmaxf(m, __shfl_xor(m, 8));
      float ssum = 0.0f;
#pragma unroll
      for (int nf = 0; nf < 16; nf++) {
        float e = __expf((acc[nf][i] - m) * 0.015625f);
        acc[nf][i] = e;
        ssum += e;
      }
      ssum += __shfl_xor(ssum, 1);
      ssum += __shfl_xor(ssum, 2);
      ssum += __shfl_xor(ssum, 4);
      ssum += __shfl_xor(ssum, 8);
      float inv = 1.0f / ssum;
#pragma unroll
      for (int nf = 0; nf < 16; nf++) avgacc[nf][i] += acc[nf][i] * inv;
    }
  }
  const long obase = (long)c * (NP * NP);
#pragma unroll
  for (int nf = 0; nf < 16; nf++)
#pragma unroll
    for (int i = 0; i < 4; i++) {
      int prow = p0 + ((lane >> 4) << 2) + i;
      int qcol = nf * 16 + (lane & 15);
      avg[obase + (long)prow * NP + qcol] = (__bf16)(avgacc[nf][i] * 0.125f);
    }
}

// chan, per p of one batch: rows c, cols f (64x64), row-stride in memory = P*D.
__global__ __launch_bounds__(256) void chan_scores(const __bf16* __restrict__ qu,
                                                   const __bf16* __restrict__ qv,
                                                   __bf16* __restrict__ avg) {
  __shared__ __bf16 ldsK[64 * 64];
  const int t = threadIdx.x, lane = t & 63, wid = t >> 6;
  const int p = blockIdx.x;
  const long pbase = (long)p * ND;
  const long cstride = (long)NP * ND;
  const int c0 = wid * 16;
  f32x4 avgacc[4];
#pragma unroll
  for (int f = 0; f < 4; f++)
#pragma unroll
    for (int q = 0; q < 4; q++) avgacc[f][q] = 0.0f;

  for (int h = 0; h < 8; h++) {
    __syncthreads();
#pragma unroll
    for (int i = 0; i < 2; i++) {  // stage K_h [64 f][64 r]
      int chunk = i * 256 + t;
      int row = chunk >> 3;
      int src = ((chunk & 7) * 16) ^ ((row & 7) << 4);
      gll16(qv + pbase + (long)row * cstride + h * 64 + (src >> 1),
            (char*)ldsK + i * 4096 + wid * 1024);
    }
    __syncthreads();
    bf16x8 aq[2];
#pragma unroll
    for (int ks = 0; ks < 2; ks++)
      aq[ks] = *(const bf16x8*)(qu + pbase + (long)(c0 + (lane & 15)) * cstride + h * 64 +
                                ks * 32 + ((lane >> 4) << 3));
    f32x4 acc[4];
#pragma unroll
    for (int f = 0; f < 4; f++)
#pragma unroll
      for (int q = 0; q < 4; q++) acc[f][q] = 0.0f;
#pragma unroll
    for (int ks = 0; ks < 2; ks++)
#pragma unroll
      for (int nf = 0; nf < 4; nf++) {
        int row = nf * 16 + (lane & 15);
        int byt = (row * 128 + ks * 64 + ((lane >> 4) << 4)) ^ ((row & 7) << 4);
        bf16x8 bfrag = *(const bf16x8*)((const char*)ldsK + byt);
        acc[nf] = __builtin_amdgcn_mfma_f32_16x16x32_bf16(aq[ks], bfrag, acc[nf], 0, 0, 0);
      }
#pragma unroll
    for (int i = 0; i < 4; i++) {
      float m = acc[0][i];
#pragma unroll
      for (int nf = 1; nf < 4; nf++) m = fmaxf(m, acc[nf][i]);
      m = fmaxf(m, __shfl_xor(m, 1));
      m = fmaxf(m, __shfl_xor(m, 2));
      m = fmaxf(m, __shfl_xor(m, 4));
      m = fmaxf(m, __shfl_xor(m, 8));
      float ssum = 0.0f;
#pragma unroll
      for (int nf = 0; nf < 4; nf++) {
        float e = __expf((acc[nf][i] - m) * 0.015625f);
        acc[nf][i] = e;
        ssum += e;
      }
      ssum += __shfl_xor(ssum, 1);
      ssum += __shfl_xor(ssum, 2);
      ssum += __shfl_xor(ssum, 4);
      ssum += __shfl_xor(ssum, 8);
      float inv = 1.0f / ssum;
#pragma unroll
      for (int nf = 0; nf < 4; nf++) avgacc[nf][i] += acc[nf][i] * inv;
    }
  }
  const long obase = (long)p * (NC * NC);
#pragma unroll
  for (int nf = 0; nf < 4; nf++)
#pragma unroll
    for (int i = 0; i < 4; i++) {
      int crow = c0 + ((lane >> 4) << 2) + i;
      int fcol = nf * 16 + (lane & 15);
      avg[obase + (long)crow * NC + fcol] = (__bf16)(avgacc[nf][i] * 0.125f);
    }
}

// ---------------- launcher ----------------

extern "C" void kernel_launch(void* const* d_in, const int* in_sizes, int n_in,
                              void* d_out, int out_size, void* d_ws, size_t ws_size,
                              hipStream_t stream) {
  const float* qz = (const float*)d_in[0];
  const float* time_u = (const float*)d_in[1];
  const float* time_v = (const float*)d_in[2];
  const float* chan_u = (const float*)d_in[3];
  const float* chan_v = (const float*)d_in[4];
  const float* pqb = (const float*)d_in[5];
  float* out_t = (float*)d_out;
  float* out_c = out_t + (long)NB * CPD;

  // workspace layout (per-batch reuse; 67,239,936 B total)
  if (ws_size < 67239936UL) return;  // clean wrong-answer signal instead of OOB fault
  char* ws = (char*)d_ws;
  __bf16* U_bf = (__bf16*)(ws + 0);             //  8,388,608 B  [mat][b][o][d]
  float* ctab = (float*)(ws + 8388608);         //     65,536 B
  float* stab = (float*)(ws + 8454144);         //     65,536 B
  __bf16* qz_bf = (__bf16*)(ws + 8519680);      // 16,777,216 B  per-batch [C*P][D]
  __bf16* qu = (__bf16*)(ws + 25296896);        // 16,777,216 B
  __bf16* qv = (__bf16*)(ws + 42074112);        // 16,777,216 B
  __bf16* avg_t = (__bf16*)(ws + 58851328);     //  8,388,608 B  (avg_c aliases)
  __bf16* avg_c = avg_t;
  __bf16* Tsh = qu;  // transpose buffer aliases qu (lifetime disjoint)

  // one-time prep
  cvt_copy<<<512, 256, 0, stream>>>(time_u, U_bf + 0L * 1048576, 1048576L);
  cvt_copy<<<512, 256, 0, stream>>>(time_v, U_bf + 1L * 1048576, 1048576L);
  cvt_copy<<<512, 256, 0, stream>>>(chan_u, U_bf + 2L * 1048576, 1048576L);
  cvt_copy<<<512, 256, 0, stream>>>(chan_v, U_bf + 3L * 1048576, 1048576L);
  fill_tables<<<64, 256, 0, stream>>>(ctab, stab);

  for (int b = 0; b < NB; b++) {
    const float* qzb = qz + (long)b * CPD;
    const __bf16* Ut = U_bf + 0L * 1048576 + (long)b * 262144;
    const __bf16* Vt = U_bf + 1L * 1048576 + (long)b * 262144;
    const __bf16* Uc = U_bf + 2L * 1048576 + (long)b * 262144;
    const __bf16* Vc = U_bf + 3L * 1048576 + (long)b * 262144;

    cvt_copy<<<4096, 256, 0, stream>>>(qzb, qz_bf, (long)CPD);

    // ---- time stage ----
    bt_gemm<128, 128, 2, 2, true><<<dim3(512, 1), 256, 0, stream>>>(
        qz_bf, 0L, 512, Ut, 0L, 512, qu, 512L, 1, 0L, 0L, 512, 4);
    bt_gemm<128, 128, 2, 2, true><<<dim3(512, 1), 256, 0, stream>>>(
        qz_bf, 0L, 512, Vt, 0L, 512, qv, 512L, 1, 0L, 0L, 512, 4);
    rope_k<<<2048, 256, 0, stream>>>(qu, ctab, stab, pqb, 0, b);
    rope_k<<<2048, 256, 0, stream>>>(qv, ctab, stab, nullptr, 0, b);
    time_scores<<<dim3(4, 64), 256, 0, stream>>>(qu, qv, avg_t);
    t_time<<<dim3(32, 64), 256, 0, stream>>>(qzb, Tsh);  // qu dead -> reuse
    // m_t[b,c] = avg_t[c] (256x256) @ qzT[c]^T : M=256 N=512 K=256
    bt_gemm<128, 128, 2, 2, false><<<dim3(8, 64), 256, 0, stream>>>(
        avg_t, 65536L, 256, Tsh, 131072L, 256,
        out_t + (long)b * CPD, 512L, 1 << 30, 0L, 131072L, 256, 4);

    // ---- chan stage ----
    bt_gemm<128, 128, 2, 2, true><<<dim3(512, 1), 256, 0, stream>>>(
        qz_bf, 0L, 512, Uc, 0L, 512, qu, 512L, 1, 0L, 0L, 512, 4);
    bt_gemm<128, 128, 2, 2, true><<<dim3(512, 1), 256, 0, stream>>>(
        qz_bf, 0L, 512, Vc, 0L, 512, qv, 512L, 1, 0L, 0L, 512, 4);
    rope_k<<<2048, 256, 0, stream>>>(qu, ctab, stab, nullptr, 1, b);
    rope_k<<<2048, 256, 0, stream>>>(qv, ctab, stab, nullptr, 1, b);
    chan_scores<<<256, 256, 0, stream>>>(qu, qv, avg_c);
    t_chan<<<dim3(8, 256), 256, 0, stream>>>(qzb, Tsh);  // qu dead again
    // m_c per p: M=64(c) N=512(d) K=64(f); C += p*D, row-stride P*D
    bt_gemm<64, 128, 1, 4, false><<<dim3(4, 256), 256, 0, stream>>>(
        avg_c, 4096L, 64, Tsh, 32768L, 64,
        out_c + (long)b * CPD, 131072L, 1 << 30, 0L, 512L, 64, 4);
  }
}